// Round 11
// baseline (202.129 us; speedup 1.0000x reference)
//
#include <hip/hip_runtime.h>

typedef __attribute__((ext_vector_type(4))) int i32x4;

#define AS1 __attribute__((address_space(1)))
#define AS3 __attribute__((address_space(3)))

constexpr int MDIM = 8192;   // batch
constexpr int NDIM = 4096;   // out features
constexpr int KDIM = 4096;   // in features

constexpr int BM = 256, BN = 256, BKB = 128;   // BKB = K-bytes (=128 i8) per tile
constexpr int NKT = KDIM / BKB;                // 32
constexpr int REP_CH = 528;                    // 16-byte chunks per replica row

__device__ __forceinline__ void gld_lds16(const signed char* g, signed char* l) {
  __builtin_amdgcn_global_load_lds((const AS1 void*)g, (AS3 void*)l, 16, 0, 0);
}

__device__ __forceinline__ int q8(float v, float inv) {
  return __float2int_rn(v * inv);
}

// ---- prep: w scale + 16-way byte-shift replica table ----
// swbuf[0] = max|params|/127.  rep16[r*REP_CH + j] = pq bytes [16j+r .. 16j+r+15],
// pq[i] = round(params[i]*127/max) for i<8191, else 0.
__global__ __launch_bounds__(256) void prep_kernel(
    const float* __restrict__ params, float* __restrict__ swbuf,
    i32x4* __restrict__ rep16) {
  __shared__ signed char pql[8480];
  __shared__ float red[4];
  int t = (int)threadIdx.x;
  float m = 0.f;
  for (int i = t; i < NDIM + KDIM - 1; i += 256) m = fmaxf(m, fabsf(params[i]));
#pragma unroll
  for (int off = 32; off >= 1; off >>= 1) m = fmaxf(m, __shfl_xor(m, off));
  if ((t & 63) == 0) red[t >> 6] = m;
  __syncthreads();
  m = fmaxf(fmaxf(red[0], red[1]), fmaxf(red[2], red[3]));
  m = fmaxf(m, 1e-30f);
  float inv = 127.0f / m;
  if (t == 0) swbuf[0] = m * (1.0f / 127.0f);
  for (int i = t; i < 8480; i += 256)
    pql[i] = (i < NDIM + KDIM - 1) ? (signed char)q8(params[i], inv) : (signed char)0;
  __syncthreads();
  for (int idx = t; idx < 16 * REP_CH; idx += 256) {
    int r = idx / REP_CH, j = idx - r * REP_CH;
    const signed char* s = &pql[16 * j + r];
    i32x4 w;
#pragma unroll
    for (int d = 0; d < 4; ++d) {
      int b0 = (unsigned char)s[4 * d + 0];
      int b1 = (unsigned char)s[4 * d + 1];
      int b2 = (unsigned char)s[4 * d + 2];
      int b3 = (unsigned char)s[4 * d + 3];
      w[d] = b0 | (b1 << 8) | (b2 << 16) | (b3 << 24);
    }
    rep16[idx] = w;
  }
}

// ---- per-row x quantization: one block per row ----
__global__ __launch_bounds__(256) void quant_x_kernel(
    const float* __restrict__ x, signed char* __restrict__ xq, float* __restrict__ sxr) {
  int row = (int)blockIdx.x;
  int t = (int)threadIdx.x;
  const float4* px = (const float4*)(x + (size_t)row * KDIM) + t * 4;
  float4 v[4];
#pragma unroll
  for (int i = 0; i < 4; ++i) v[i] = px[i];
  float m = 0.f;
#pragma unroll
  for (int i = 0; i < 4; ++i)
    m = fmaxf(fmaxf(fmaxf(fabsf(v[i].x), fabsf(v[i].y)), fmaxf(fabsf(v[i].z), fabsf(v[i].w))), m);
#pragma unroll
  for (int off = 32; off >= 1; off >>= 1) m = fmaxf(m, __shfl_xor(m, off));
  __shared__ float red[4];
  if ((t & 63) == 0) red[t >> 6] = m;
  __syncthreads();
  m = fmaxf(fmaxf(red[0], red[1]), fmaxf(red[2], red[3]));
  m = fmaxf(m, 1e-30f);
  float inv = 127.0f / m;
  if (t == 0) sxr[row] = m * (1.0f / 127.0f);
  i32x4 w;
#pragma unroll
  for (int i = 0; i < 4; ++i) {
    int q0 = q8(v[i].x, inv), q1 = q8(v[i].y, inv), q2 = q8(v[i].z, inv), q3 = q8(v[i].w, inv);
    w[i] = (q0 & 0xff) | ((q1 & 0xff) << 8) | ((q2 & 0xff) << 16) | ((q3 & 0xff) << 24);
  }
  *(i32x4*)(xq + (size_t)row * KDIM + t * 16) = w;
}

// ========== 256x256 i8 GEMM; A via LDS (R7 geometry), B = 1 dwordx4/frag from rep16 ==========
// C = (Aq * Bq^T) * sx[row] * sw + bias ;  Bq[col][k] = pq[4095 - col + k].
// Lane's B fragment = 16 consecutive pq bytes at offset ≡ idx0 (mod 16) ->
// single aligned global_load_dwordx4 from replica r = idx0 & 15. LDS holds A only.
__global__ __launch_bounds__(512, 2) void toep_gemm_i8(
    const signed char* __restrict__ A,
    const i32x4* __restrict__ rep16,
    const float* __restrict__ bias,
    const float* __restrict__ sxr,
    const float* __restrict__ swbuf,
    float* __restrict__ C)
{
  __shared__ signed char sA[2][BM * BKB];   // 2 x 32 KiB

  constexpr int NBM = MDIM / BM;   // 32
  constexpr int NBN = NDIM / BN;   // 16
  constexpr int NWG = NBM * NBN;   // 512
  int bid = (int)blockIdx.x;
  int swz = (bid & 7) * (NWG >> 3) + (bid >> 3);
  int bm = swz / NBN, bn = swz % NBN;
  int m0 = bm * BM, n0 = bn * BN;

  int t = (int)threadIdx.x;
  int lane = t & 63, wid = t >> 6;
  int wm = wid >> 2, wn = wid & 3;     // 2 (M) x 4 (N) waves; 128x64 per wave
  int lr = lane & 15, lk = lane >> 4;

  // A staging: dest linear t*16B, source slot pre-swizzled (involution p^(row&7))
  int scol = (((t & 7) ^ ((t >> 3) & 7)) << 4);   // bytes
  const signed char* gA = A + (size_t)(m0 + (t >> 3)) * KDIM + scol;

#define STG_A(c, kt, R0) gld_lds16(gA + (size_t)(R0) * KDIM + (kt) * BKB, &sA[c][(R0) * BKB + t * 16])

  // A ds_read addressing (swizzled, bytes) — R7/R9-proven zero-conflict geometry
  int aswz = (lr & 7) << 4;
  int c0 = (lk * 16) ^ aswz;        // k-bytes 0..63
  int c1 = (64 + lk * 16) ^ aswz;   // k-bytes 64..127

  // B addressing: idx0 = 4095 - (n0 + wn*64 + lr) + lk*16; fragment pq-offsets are
  // idx0 - 32nsub - 16ni + 64h + 128kt (all ≡ idx0 mod 16).
  int idx0 = 4095 - (n0 + wn * 64 + lr) + lk * 16;
  const i32x4* pqb = rep16 + (idx0 & 15) * REP_CH + (idx0 >> 4);
  // chunk delta = -2*nsub - ni + 4*h  (+8 per K-tile)

  i32x4 avA[4][2], avB[4][2];   // A fragments msub0 / msub1
  i32x4 bvA[2][2], bvB[2][2];   // B fragments nsub0 / nsub1 ([ni][half])
  i32x4 acc[8][4];
#pragma unroll
  for (int i = 0; i < 8; ++i)
#pragma unroll
    for (int j = 0; j < 4; ++j) acc[i][j] = (i32x4){0, 0, 0, 0};

#define LDA_GRP(c, msub, AV) do { \
  _Pragma("unroll") \
  for (int mi = 0; mi < 4; ++mi) { \
    const signed char* p_ = &sA[c][(wm * 128 + (msub) * 64 + mi * 16 + lr) * BKB]; \
    AV[mi][0] = *(const i32x4*)(p_ + c0); \
    AV[mi][1] = *(const i32x4*)(p_ + c1); \
  } } while (0)

  // 4 global_load_dwordx4 from the replica table
#define LDB_GRP(BV, NSUB, TD) do { \
  _Pragma("unroll") \
  for (int ni = 0; ni < 2; ++ni) \
    _Pragma("unroll") \
    for (int h = 0; h < 2; ++h) \
      BV[ni][h] = pqb[(TD) - 2 * (NSUB) - ni + 4 * h]; \
} while (0)

#define MMA_Q(msub, nsub, AV, BV) do { \
  __builtin_amdgcn_s_setprio(1); \
  _Pragma("unroll") \
  for (int mi = 0; mi < 4; ++mi) \
    _Pragma("unroll") \
    for (int ni = 0; ni < 2; ++ni) { \
      acc[(msub) * 4 + mi][(nsub) * 2 + ni] = __builtin_amdgcn_mfma_i32_16x16x64_i8( \
          AV[mi][0], BV[ni][0], acc[(msub) * 4 + mi][(nsub) * 2 + ni], 0, 0, 0); \
      acc[(msub) * 4 + mi][(nsub) * 2 + ni] = __builtin_amdgcn_mfma_i32_16x16x64_i8( \
          AV[mi][1], BV[ni][1], acc[(msub) * 4 + mi][(nsub) * 2 + ni], 0, 0, 0); \
    } \
  __builtin_amdgcn_s_setprio(0); \
} while (0)

#define SB0() __builtin_amdgcn_sched_barrier(0)
#define BAR() __builtin_amdgcn_s_barrier()

  // Prologue: bvA(0) [4]; A-DMA(0) [4]; drain all; barrier; pre-issue avA(0) ds reads.
  LDB_GRP(bvA, 0, 0); SB0();
  STG_A(0, 0, 0); STG_A(0, 0, 64); STG_A(0, 0, 128); STG_A(0, 0, 192);
  asm volatile("s_waitcnt vmcnt(0)" ::: "memory");
  BAR();
  LDA_GRP(0, 0, avA); SB0();

  // Steady VM FIFO: enter [bvA(kt):4]; +bvB(4) +DMA(4) -> W0 vmcnt(8) drains bvA;
  // after Q10 +bvA'(4) -> W2 vmcnt(8) drains bvB; pre-BAR vmcnt(4) drains DMA;
  // exit [bvA':4].  DS FIFO: [avA:8][avB:8] -> W0 lgkm(8), W1 lgkm(0).
  // All reads of buf c drain by W1; BAR precedes next tile's DMA into c -> race-free.
#define TILE(c, kt) do { \
  const bool st_ = (kt) + 1 < NKT; \
  LDB_GRP(bvB, 1, 0); SB0(); \
  if (st_) { STG_A((c) ^ 1, (kt) + 1, 0); STG_A((c) ^ 1, (kt) + 1, 64); \
             STG_A((c) ^ 1, (kt) + 1, 128); STG_A((c) ^ 1, (kt) + 1, 192); SB0(); } \
  LDA_GRP(c, 1, avB); SB0(); \
  /* W0: Q00 needs avA + bvA */ \
  if (st_) { asm volatile("s_waitcnt vmcnt(8)" ::: "memory"); } \
  else     { asm volatile("s_waitcnt vmcnt(4)" ::: "memory"); } \
  asm volatile("s_waitcnt lgkmcnt(8)" ::: "memory"); SB0(); \
  MMA_Q(0, 0, avA, bvA); \
  /* W1: Q10 needs avB */ \
  asm volatile("s_waitcnt lgkmcnt(0)" ::: "memory"); SB0(); \
  MMA_Q(1, 0, avB, bvA); \
  /* bvA regs free: prefetch bvA(kt+1) */ \
  if (st_) { LDB_GRP(bvA, 0, 8); SB0(); } \
  /* W2: Q01 needs bvB */ \
  if (st_) { asm volatile("s_waitcnt vmcnt(8)" ::: "memory"); } \
  else     { asm volatile("s_waitcnt vmcnt(0)" ::: "memory"); } \
  SB0(); \
  MMA_Q(0, 1, avA, bvB); \
  /* drain DMA; barrier; read-ahead avA(kt+1); Q11 covers the drain */ \
  if (st_) { asm volatile("s_waitcnt vmcnt(4)" ::: "memory"); } \
  BAR(); \
  if (st_) { LDA_GRP((c) ^ 1, 0, avA); SB0(); pqb += 8; } \
  MMA_Q(1, 1, avB, bvB); \
} while (0)

  for (int kt = 0; kt < NKT; kt += 2) {
    TILE(0, kt);
    TILE(1, kt + 1);
  }

  // Epilogue: C/D col = lane&15, row = (lane>>4)*4 + reg; out = acc*sx[row]*sw + bias
  float sw = swbuf[0];
  float bvv[4];
#pragma unroll
  for (int fn = 0; fn < 4; ++fn) bvv[fn] = bias[n0 + wn * 64 + fn * 16 + lr];
#pragma unroll
  for (int fm = 0; fm < 8; ++fm) {
    int row0 = m0 + wm * 128 + fm * 16 + lk * 4;
    float sx_[4];
#pragma unroll
    for (int r = 0; r < 4; ++r) sx_[r] = sxr[row0 + r] * sw;
#pragma unroll
    for (int fn = 0; fn < 4; ++fn) {
      int col = n0 + wn * 64 + fn * 16 + lr;
#pragma unroll
      for (int r = 0; r < 4; ++r)
        C[(size_t)(row0 + r) * NDIM + col] = (float)acc[fm][fn][r] * sx_[r] + bvv[fn];
    }
  }
#undef TILE
#undef MMA_Q
#undef LDB_GRP
#undef LDA_GRP
#undef STG_A
#undef SB0
#undef BAR
}

// ---- exact-f32 fallback (used only if ws too small) ----
__global__ __launch_bounds__(256) void toep_f32_fallback(
    const float* __restrict__ X, const float* __restrict__ P,
    const float* __restrict__ bias, float* __restrict__ C)
{
  constexpr int TM = 64, TN = 64, TK = 32;
  __shared__ float xs[TM][TK + 1];
  __shared__ float win[TN + TK];
  int bm = blockIdx.x / (NDIM / TN);
  int bn = blockIdx.x % (NDIM / TN);
  int m0 = bm * TM, n0 = bn * TN;
  int t = (int)threadIdx.x;
  int tx = t & 15, ty = t >> 4;
  float acc[4][4] = {};
  for (int k0 = 0; k0 < KDIM; k0 += TK) {
    __syncthreads();
    for (int i = t; i < TM * TK; i += 256) {
      int r = i >> 5, c = i & 31;
      xs[r][c] = X[(size_t)(m0 + r) * KDIM + k0 + c];
    }
    if (t < TN + TK - 1) win[t] = P[(NDIM - 1) - n0 - (TN - 1) + k0 + t];
    __syncthreads();
    for (int kk = 0; kk < TK; ++kk) {
      float xv[4];
#pragma unroll
      for (int i = 0; i < 4; ++i) xv[i] = xs[ty * 4 + i][kk];
#pragma unroll
      for (int j = 0; j < 4; ++j) {
        float wv = win[kk + (TN - 1) - (tx * 4 + j)];
#pragma unroll
        for (int i = 0; i < 4; ++i) acc[i][j] += xv[i] * wv;
      }
    }
  }
#pragma unroll
  for (int i = 0; i < 4; ++i)
#pragma unroll
    for (int j = 0; j < 4; ++j)
      C[(size_t)(m0 + ty * 4 + i) * NDIM + n0 + tx * 4 + j] = acc[i][j] + bias[n0 + tx * 4 + j];
}

extern "C" void kernel_launch(void* const* d_in, const int* in_sizes, int n_in,
                              void* d_out, int out_size, void* d_ws, size_t ws_size,
                              hipStream_t stream) {
  const float* x = (const float*)d_in[0];
  const float* params = (const float*)d_in[1];
  const float* bias = (const float*)d_in[2];
  float* out = (float*)d_out;

  const size_t xq_off = 0;
  const size_t pq_off = (size_t)MDIM * KDIM;               // 32 MiB
  const size_t sx_off = pq_off + 16 * REP_CH * 16 + 64;    // table 135168 B (+pad)
  const size_t sw_off = sx_off + (size_t)MDIM * 4;
  const size_t need = sw_off + 64;

  if (ws_size >= need) {
    signed char* xq = (signed char*)d_ws + xq_off;
    i32x4* rep16 = (i32x4*)((char*)d_ws + pq_off);
    float* sxr = (float*)((char*)d_ws + sx_off);
    float* swbuf = (float*)((char*)d_ws + sw_off);
    prep_kernel<<<1, 256, 0, stream>>>(params, swbuf, rep16);
    quant_x_kernel<<<MDIM, 256, 0, stream>>>(x, xq, sxr);
    toep_gemm_i8<<<(MDIM / BM) * (NDIM / BN), 512, 0, stream>>>(xq, rep16, bias, sxr, swbuf, out);
  } else {
    toep_f32_fallback<<<(MDIM / 64) * (NDIM / 64), 256, 0, stream>>>(x, params, bias, out);
  }
}

// Round 12
// 158.669 us; speedup vs baseline: 1.2739x; 1.2739x over previous
//
#include <hip/hip_runtime.h>

typedef __attribute__((ext_vector_type(4))) int i32x4;

#define AS1 __attribute__((address_space(1)))
#define AS3 __attribute__((address_space(3)))

constexpr int MDIM = 8192;   // batch
constexpr int NDIM = 4096;   // out features
constexpr int KDIM = 4096;   // in features

constexpr int BM = 256, BN = 256, BKB = 128;   // BKB = K-bytes (=128 i8) per tile
constexpr int NKT = KDIM / BKB;                // 32
constexpr int REP_CH = 528;                    // global table: 16-B chunks per replica
constexpr int WIN_CH = 273;                    // LDS window: 272 data chunks + 1 pad (bank spread)

__device__ __forceinline__ void gld_lds16(const signed char* g, signed char* l) {
  __builtin_amdgcn_global_load_lds((const AS1 void*)g, (AS3 void*)l, 16, 0, 0);
}

__device__ __forceinline__ int q8(float v, float inv) {
  return __float2int_rn(v * inv);
}

// ---- prep: w scale + 16-way byte-shift replica table (global) ----
// swbuf[0] = max|params|/127.  rep16[r*REP_CH + j] = pq bytes [16j+r .. 16j+r+15],
// pq[i] = round(params[i]*127/max) for i<8191, else 0.
__global__ __launch_bounds__(256) void prep_kernel(
    const float* __restrict__ params, float* __restrict__ swbuf,
    i32x4* __restrict__ rep16) {
  __shared__ signed char pql[8480];
  __shared__ float red[4];
  int t = (int)threadIdx.x;
  float m = 0.f;
  for (int i = t; i < NDIM + KDIM - 1; i += 256) m = fmaxf(m, fabsf(params[i]));
#pragma unroll
  for (int off = 32; off >= 1; off >>= 1) m = fmaxf(m, __shfl_xor(m, off));
  if ((t & 63) == 0) red[t >> 6] = m;
  __syncthreads();
  m = fmaxf(fmaxf(red[0], red[1]), fmaxf(red[2], red[3]));
  m = fmaxf(m, 1e-30f);
  float inv = 127.0f / m;
  if (t == 0) swbuf[0] = m * (1.0f / 127.0f);
  for (int i = t; i < 8480; i += 256)
    pql[i] = (i < NDIM + KDIM - 1) ? (signed char)q8(params[i], inv) : (signed char)0;
  __syncthreads();
  for (int idx = t; idx < 16 * REP_CH; idx += 256) {
    int r = idx / REP_CH, j = idx - r * REP_CH;
    const signed char* s = &pql[16 * j + r];
    i32x4 w;
#pragma unroll
    for (int d = 0; d < 4; ++d) {
      int b0 = (unsigned char)s[4 * d + 0];
      int b1 = (unsigned char)s[4 * d + 1];
      int b2 = (unsigned char)s[4 * d + 2];
      int b3 = (unsigned char)s[4 * d + 3];
      w[d] = b0 | (b1 << 8) | (b2 << 16) | (b3 << 24);
    }
    rep16[idx] = w;
  }
}

// ---- per-row x quantization: one block per row ----
__global__ __launch_bounds__(256) void quant_x_kernel(
    const float* __restrict__ x, signed char* __restrict__ xq, float* __restrict__ sxr) {
  int row = (int)blockIdx.x;
  int t = (int)threadIdx.x;
  const float4* px = (const float4*)(x + (size_t)row * KDIM) + t * 4;
  float4 v[4];
#pragma unroll
  for (int i = 0; i < 4; ++i) v[i] = px[i];
  float m = 0.f;
#pragma unroll
  for (int i = 0; i < 4; ++i)
    m = fmaxf(fmaxf(fmaxf(fabsf(v[i].x), fabsf(v[i].y)), fmaxf(fabsf(v[i].z), fabsf(v[i].w))), m);
#pragma unroll
  for (int off = 32; off >= 1; off >>= 1) m = fmaxf(m, __shfl_xor(m, off));
  __shared__ float red[4];
  if ((t & 63) == 0) red[t >> 6] = m;
  __syncthreads();
  m = fmaxf(fmaxf(red[0], red[1]), fmaxf(red[2], red[3]));
  m = fmaxf(m, 1e-30f);
  float inv = 127.0f / m;
  if (t == 0) sxr[row] = m * (1.0f / 127.0f);
  i32x4 w;
#pragma unroll
  for (int i = 0; i < 4; ++i) {
    int q0 = q8(v[i].x, inv), q1 = q8(v[i].y, inv), q2 = q8(v[i].z, inv), q3 = q8(v[i].w, inv);
    w[i] = (q0 & 0xff) | ((q1 & 0xff) << 8) | ((q2 & 0xff) << 16) | ((q3 & 0xff) << 24);
  }
  *(i32x4*)(xq + (size_t)row * KDIM + t * 16) = w;
}

// ========== 256x256 i8 GEMM; A via LDS dbuf (R7 geometry), B via LDS pq-window ==========
// C = (Aq * Bq^T) * sx[row] * sw + bias ;  Bq[col][k] = pq[4095 - col + k].
// sPQ: 16 replicas x 273 chunks (padded stride -> 8-slot bank spread, R9-class
// zero-conflict profile). Staged once per block (69.9 KB). A: 2 x 32 KiB dbuf.
// Per tile: only 4 A-DMA VM ops; B fragments are ds_read_b128 with imm offsets.
__global__ __launch_bounds__(512, 2) void toep_gemm_i8(
    const signed char* __restrict__ A,
    const i32x4* __restrict__ rep16,
    const float* __restrict__ bias,
    const float* __restrict__ sxr,
    const float* __restrict__ swbuf,
    float* __restrict__ C)
{
  __shared__ signed char sA[2][BM * BKB];          // 65536 B
  __shared__ signed char sPQ[16 * WIN_CH * 16];    // 69888 B   (total 135424 B)

  constexpr int NBM = MDIM / BM;   // 32
  constexpr int NBN = NDIM / BN;   // 16
  constexpr int NWG = NBM * NBN;   // 512
  int bid = (int)blockIdx.x;
  int swz = (bid & 7) * (NWG >> 3) + (bid >> 3);
  int bm = swz / NBN, bn = swz % NBN;
  int m0 = bm * BM, n0 = bn * BN;

  int t = (int)threadIdx.x;
  int lane = t & 63, wid = t >> 6;
  int wm = wid >> 2, wn = wid & 3;     // 2 (M) x 4 (N) waves; 128x64 per wave
  int lr = lane & 15, lk = lane >> 4;

  // A staging: dest linear t*16B, source slot pre-swizzled (involution p^(row&7))
  int scol = (((t & 7) ^ ((t >> 3) & 7)) << 4);   // bytes
  const signed char* gA = A + (size_t)(m0 + (t >> 3)) * KDIM + scol;

#define STG_A(c, kt, R0) gld_lds16(gA + (size_t)(R0) * KDIM + (kt) * BKB, &sA[c][(R0) * BKB + t * 16])

  // A ds_read addressing (swizzled, bytes) — R7/R9-proven zero-conflict geometry
  int aswz = (lr & 7) << 4;
  int c0 = (lk * 16) ^ aswz;        // k-bytes 0..63
  int c1 = (64 + lk * 16) ^ aswz;   // k-bytes 64..127

  // B window addressing: block idx range = [3840-n0, 8191-n0]; j0 = window base chunk.
  // idx0 = 4095 - (n0 + wn*64 + lr) + lk*16; replica r = idx0 & 15 (per-lane const).
  // Fragment chunk = (idx0>>4) - j0 + (-2nsub - ni + 4h) + 8kt  in [0,270].
  int j0 = (3840 - n0) >> 4;
  int idx0 = 4095 - (n0 + wn * 64 + lr) + lk * 16;
  const signed char* pB = &sPQ[((idx0 & 15) * WIN_CH + ((idx0 >> 4) - j0) - 3) * 16];
  // imm chunk offset = 3 - 2*nsub - ni + 4*h  (in [0,7]); pB += 128 per K-tile.

  i32x4 avA[4][2], avB[4][2];   // A fragments msub0 / msub1
  i32x4 bvA[2][2], bvB[2][2];   // B fragments nsub0 / nsub1 ([ni][half])
  i32x4 acc[8][4];
#pragma unroll
  for (int i = 0; i < 8; ++i)
#pragma unroll
    for (int j = 0; j < 4; ++j) acc[i][j] = (i32x4){0, 0, 0, 0};

#define LDA_GRP(c, msub, AV) do { \
  _Pragma("unroll") \
  for (int mi = 0; mi < 4; ++mi) { \
    const signed char* p_ = &sA[c][(wm * 128 + (msub) * 64 + mi * 16 + lr) * BKB]; \
    AV[mi][0] = *(const i32x4*)(p_ + c0); \
    AV[mi][1] = *(const i32x4*)(p_ + c1); \
  } } while (0)

  // 4 ds_read_b128 from the LDS pq window (imm offsets, all >= 0)
#define LDB_GRP(BV, NSUB, PBP) do { \
  _Pragma("unroll") \
  for (int ni = 0; ni < 2; ++ni) \
    _Pragma("unroll") \
    for (int h = 0; h < 2; ++h) \
      BV[ni][h] = *(const i32x4*)((PBP) + (3 - 2 * (NSUB) - ni + 4 * h) * 16); \
} while (0)

#define MMA_Q(msub, nsub, AV, BV) do { \
  __builtin_amdgcn_s_setprio(1); \
  _Pragma("unroll") \
  for (int mi = 0; mi < 4; ++mi) \
    _Pragma("unroll") \
    for (int ni = 0; ni < 2; ++ni) { \
      acc[(msub) * 4 + mi][(nsub) * 2 + ni] = __builtin_amdgcn_mfma_i32_16x16x64_i8( \
          AV[mi][0], BV[ni][0], acc[(msub) * 4 + mi][(nsub) * 2 + ni], 0, 0, 0); \
      acc[(msub) * 4 + mi][(nsub) * 2 + ni] = __builtin_amdgcn_mfma_i32_16x16x64_i8( \
          AV[mi][1], BV[ni][1], acc[(msub) * 4 + mi][(nsub) * 2 + ni], 0, 0, 0); \
    } \
  __builtin_amdgcn_s_setprio(0); \
} while (0)

#define SB0() __builtin_amdgcn_sched_barrier(0)
#define BAR() __builtin_amdgcn_s_barrier()

  // Prologue: stage sPQ window (16*273 = 4368 chunks, 9 sweeps) + A tile 0; drain; BAR.
  for (int s = 0; s < 9; ++s) {
    int cc = s * 512 + t;
    if (cc < 16 * WIN_CH) {
      int rr = (int)(((unsigned long long)(unsigned)cc * 15732791ull) >> 32);  // cc/273
      int jj = cc - rr * WIN_CH;
      gld_lds16((const signed char*)(rep16 + rr * REP_CH + j0 + jj), &sPQ[cc * 16]);
    }
  }
  STG_A(0, 0, 0); STG_A(0, 0, 64); STG_A(0, 0, 128); STG_A(0, 0, 192);
  asm volatile("s_waitcnt vmcnt(0)" ::: "memory");
  BAR();
  LDB_GRP(bvA, 0, pB); SB0();
  LDA_GRP(0, 0, avA); SB0();   // DS FIFO: [bvA:4][avA:8]

  // DS FIFO at waits: entry [bvA4, avA8]; +bvB4 +avB8 -> W0 lgkm(12) drains entry set;
  // W1 lgkm(0) drains bvB+avB. All reads of buf c done by W1; vmcnt(0)+BAR then
  // releases next-tile DMA into c (race-free). bvA' read-ahead (read-only table, no
  // WAR) issues pre-BAR; avA' (buf c^1, staged this tile) issues post-BAR.
#define TILE(c, kt) do { \
  const bool st_ = (kt) + 1 < NKT; \
  LDB_GRP(bvB, 1, pB); SB0(); \
  if (st_) { STG_A((c) ^ 1, (kt) + 1, 0); STG_A((c) ^ 1, (kt) + 1, 64); \
             STG_A((c) ^ 1, (kt) + 1, 128); STG_A((c) ^ 1, (kt) + 1, 192); SB0(); } \
  LDA_GRP(c, 1, avB); SB0(); \
  asm volatile("s_waitcnt lgkmcnt(12)" ::: "memory"); SB0(); \
  MMA_Q(0, 0, avA, bvA); \
  asm volatile("s_waitcnt lgkmcnt(0)" ::: "memory"); SB0(); \
  MMA_Q(1, 0, avB, bvA); \
  if (st_) { LDB_GRP(bvA, 0, pB + 128); SB0(); } \
  MMA_Q(0, 1, avA, bvB); \
  if (st_) { asm volatile("s_waitcnt vmcnt(0)" ::: "memory"); } \
  BAR(); \
  if (st_) { LDA_GRP((c) ^ 1, 0, avA); SB0(); pB += 128; } \
  MMA_Q(1, 1, avB, bvB); \
} while (0)

  for (int kt = 0; kt < NKT; kt += 2) {
    TILE(0, kt);
    TILE(1, kt + 1);
  }

  // Epilogue: C/D col = lane&15, row = (lane>>4)*4 + reg; out = acc*sx[row]*sw + bias
  float sw = swbuf[0];
  float bvv[4];
#pragma unroll
  for (int fn = 0; fn < 4; ++fn) bvv[fn] = bias[n0 + wn * 64 + fn * 16 + lr];
#pragma unroll
  for (int fm = 0; fm < 8; ++fm) {
    int row0 = m0 + wm * 128 + fm * 16 + lk * 4;
    float sx_[4];
#pragma unroll
    for (int r = 0; r < 4; ++r) sx_[r] = sxr[row0 + r] * sw;
#pragma unroll
    for (int fn = 0; fn < 4; ++fn) {
      int col = n0 + wn * 64 + fn * 16 + lr;
#pragma unroll
      for (int r = 0; r < 4; ++r)
        C[(size_t)(row0 + r) * NDIM + col] = (float)acc[fm][fn][r] * sx_[r] + bvv[fn];
    }
  }
#undef TILE
#undef MMA_Q
#undef LDB_GRP
#undef LDA_GRP
#undef STG_A
#undef SB0
#undef BAR
}

// ---- exact-f32 fallback (used only if ws too small) ----
__global__ __launch_bounds__(256) void toep_f32_fallback(
    const float* __restrict__ X, const float* __restrict__ P,
    const float* __restrict__ bias, float* __restrict__ C)
{
  constexpr int TM = 64, TN = 64, TK = 32;
  __shared__ float xs[TM][TK + 1];
  __shared__ float win[TN + TK];
  int bm = blockIdx.x / (NDIM / TN);
  int bn = blockIdx.x % (NDIM / TN);
  int m0 = bm * TM, n0 = bn * TN;
  int t = (int)threadIdx.x;
  int tx = t & 15, ty = t >> 4;
  float acc[4][4] = {};
  for (int k0 = 0; k0 < KDIM; k0 += TK) {
    __syncthreads();
    for (int i = t; i < TM * TK; i += 256) {
      int r = i >> 5, c = i & 31;
      xs[r][c] = X[(size_t)(m0 + r) * KDIM + k0 + c];
    }
    if (t < TN + TK - 1) win[t] = P[(NDIM - 1) - n0 - (TN - 1) + k0 + t];
    __syncthreads();
    for (int kk = 0; kk < TK; ++kk) {
      float xv[4];
#pragma unroll
      for (int i = 0; i < 4; ++i) xv[i] = xs[ty * 4 + i][kk];
#pragma unroll
      for (int j = 0; j < 4; ++j) {
        float wv = win[kk + (TN - 1) - (tx * 4 + j)];
#pragma unroll
        for (int i = 0; i < 4; ++i) acc[i][j] += xv[i] * wv;
      }
    }
  }
#pragma unroll
  for (int i = 0; i < 4; ++i)
#pragma unroll
    for (int j = 0; j < 4; ++j)
      C[(size_t)(m0 + ty * 4 + i) * NDIM + n0 + tx * 4 + j] = acc[i][j] + bias[n0 + tx * 4 + j];
}

extern "C" void kernel_launch(void* const* d_in, const int* in_sizes, int n_in,
                              void* d_out, int out_size, void* d_ws, size_t ws_size,
                              hipStream_t stream) {
  const float* x = (const float*)d_in[0];
  const float* params = (const float*)d_in[1];
  const float* bias = (const float*)d_in[2];
  float* out = (float*)d_out;

  const size_t xq_off = 0;
  const size_t pq_off = (size_t)MDIM * KDIM;               // 32 MiB
  const size_t sx_off = pq_off + 16 * REP_CH * 16 + 64;    // table 135168 B (+pad)
  const size_t sw_off = sx_off + (size_t)MDIM * 4;
  const size_t need = sw_off + 64;

  if (ws_size >= need) {
    signed char* xq = (signed char*)d_ws + xq_off;
    i32x4* rep16 = (i32x4*)((char*)d_ws + pq_off);
    float* sxr = (float*)((char*)d_ws + sx_off);
    float* swbuf = (float*)((char*)d_ws + sw_off);
    prep_kernel<<<1, 256, 0, stream>>>(params, swbuf, rep16);
    quant_x_kernel<<<MDIM, 256, 0, stream>>>(x, xq, sxr);
    toep_gemm_i8<<<(MDIM / BM) * (NDIM / BN), 512, 0, stream>>>(xq, rep16, bias, sxr, swbuf, out);
  } else {
    toep_f32_fallback<<<(MDIM / 64) * (NDIM / 64), 256, 0, stream>>>(x, params, bias, out);
  }
}

// Round 13
// 154.158 us; speedup vs baseline: 1.3112x; 1.0293x over previous
//
#include <hip/hip_runtime.h>

typedef __attribute__((ext_vector_type(4))) int i32x4;

#define AS1 __attribute__((address_space(1)))
#define AS3 __attribute__((address_space(3)))

constexpr int MDIM = 8192;   // batch
constexpr int NDIM = 4096;   // out features
constexpr int KDIM = 4096;   // in features

constexpr int BM = 256, BN = 256, BKB = 128;   // BKB = K-bytes (=128 i8) per tile
constexpr int NKT = KDIM / BKB;                // 32
constexpr int REP_CH = 528;                    // global table: 16-B chunks per replica
constexpr int WIN_CH = 273;                    // LDS window: 272 data chunks + 1 pad

__device__ __forceinline__ void gld_lds16(const signed char* g, signed char* l) {
  __builtin_amdgcn_global_load_lds((const AS1 void*)g, (AS3 void*)l, 16, 0, 0);
}

__device__ __forceinline__ int q8(float v, float inv) {
  return __float2int_rn(v * inv);
}

// ---- prep: w scale + 16-way byte-shift replica table (global) ----
__global__ __launch_bounds__(256) void prep_kernel(
    const float* __restrict__ params, float* __restrict__ swbuf,
    i32x4* __restrict__ rep16) {
  __shared__ signed char pql[8480];
  __shared__ float red[4];
  int t = (int)threadIdx.x;
  float m = 0.f;
  for (int i = t; i < NDIM + KDIM - 1; i += 256) m = fmaxf(m, fabsf(params[i]));
#pragma unroll
  for (int off = 32; off >= 1; off >>= 1) m = fmaxf(m, __shfl_xor(m, off));
  if ((t & 63) == 0) red[t >> 6] = m;
  __syncthreads();
  m = fmaxf(fmaxf(red[0], red[1]), fmaxf(red[2], red[3]));
  m = fmaxf(m, 1e-30f);
  float inv = 127.0f / m;
  if (t == 0) swbuf[0] = m * (1.0f / 127.0f);
  for (int i = t; i < 8480; i += 256)
    pql[i] = (i < NDIM + KDIM - 1) ? (signed char)q8(params[i], inv) : (signed char)0;
  __syncthreads();
  for (int idx = t; idx < 16 * REP_CH; idx += 256) {
    int r = idx / REP_CH, j = idx - r * REP_CH;
    const signed char* s = &pql[16 * j + r];
    i32x4 w;
#pragma unroll
    for (int d = 0; d < 4; ++d) {
      int b0 = (unsigned char)s[4 * d + 0];
      int b1 = (unsigned char)s[4 * d + 1];
      int b2 = (unsigned char)s[4 * d + 2];
      int b3 = (unsigned char)s[4 * d + 3];
      w[d] = b0 | (b1 << 8) | (b2 << 16) | (b3 << 24);
    }
    rep16[idx] = w;
  }
}

// ---- per-row x quantization: one block per row ----
__global__ __launch_bounds__(256) void quant_x_kernel(
    const float* __restrict__ x, signed char* __restrict__ xq, float* __restrict__ sxr) {
  int row = (int)blockIdx.x;
  int t = (int)threadIdx.x;
  const float4* px = (const float4*)(x + (size_t)row * KDIM) + t * 4;
  float4 v[4];
#pragma unroll
  for (int i = 0; i < 4; ++i) v[i] = px[i];
  float m = 0.f;
#pragma unroll
  for (int i = 0; i < 4; ++i)
    m = fmaxf(fmaxf(fmaxf(fabsf(v[i].x), fabsf(v[i].y)), fmaxf(fabsf(v[i].z), fabsf(v[i].w))), m);
#pragma unroll
  for (int off = 32; off >= 1; off >>= 1) m = fmaxf(m, __shfl_xor(m, off));
  __shared__ float red[4];
  if ((t & 63) == 0) red[t >> 6] = m;
  __syncthreads();
  m = fmaxf(fmaxf(red[0], red[1]), fmaxf(red[2], red[3]));
  m = fmaxf(m, 1e-30f);
  float inv = 127.0f / m;
  if (t == 0) sxr[row] = m * (1.0f / 127.0f);
  i32x4 w;
#pragma unroll
  for (int i = 0; i < 4; ++i) {
    int q0 = q8(v[i].x, inv), q1 = q8(v[i].y, inv), q2 = q8(v[i].z, inv), q3 = q8(v[i].w, inv);
    w[i] = (q0 & 0xff) | ((q1 & 0xff) << 8) | ((q2 & 0xff) << 16) | ((q3 & 0xff) << 24);
  }
  *(i32x4*)(xq + (size_t)row * KDIM + t * 16) = w;
}

// ========== 256x256 i8 GEMM; A via LDS dbuf, B via LDS pq-window ==========
// R12 structure with burst-smoothed quadrant order Q00->Q01->Q10->Q11:
// no mid-tile full drain of a 12-read burst; every counted wait's burst fits
// (or nearly fits) under the preceding MFMA cover.
__global__ __launch_bounds__(512, 2) void toep_gemm_i8(
    const signed char* __restrict__ A,
    const i32x4* __restrict__ rep16,
    const float* __restrict__ bias,
    const float* __restrict__ sxr,
    const float* __restrict__ swbuf,
    float* __restrict__ C)
{
  __shared__ signed char sA[2][BM * BKB];          // 65536 B
  __shared__ signed char sPQ[16 * WIN_CH * 16];    // 69888 B

  constexpr int NBM = MDIM / BM;   // 32
  constexpr int NBN = NDIM / BN;   // 16
  constexpr int NWG = NBM * NBN;   // 512
  int bid = (int)blockIdx.x;
  int swz = (bid & 7) * (NWG >> 3) + (bid >> 3);
  int bm = swz / NBN, bn = swz % NBN;
  int m0 = bm * BM, n0 = bn * BN;

  int t = (int)threadIdx.x;
  int lane = t & 63, wid = t >> 6;
  int wm = wid >> 2, wn = wid & 3;     // 2 (M) x 4 (N) waves; 128x64 per wave
  int lr = lane & 15, lk = lane >> 4;

  int scol = (((t & 7) ^ ((t >> 3) & 7)) << 4);   // bytes
  const signed char* gA = A + (size_t)(m0 + (t >> 3)) * KDIM + scol;

#define STG_A(c, kt, R0) gld_lds16(gA + (size_t)(R0) * KDIM + (kt) * BKB, &sA[c][(R0) * BKB + t * 16])

  int aswz = (lr & 7) << 4;
  int c0 = (lk * 16) ^ aswz;        // k-bytes 0..63
  int c1 = (64 + lk * 16) ^ aswz;   // k-bytes 64..127

  int j0 = (3840 - n0) >> 4;
  int idx0 = 4095 - (n0 + wn * 64 + lr) + lk * 16;
  const signed char* pB = &sPQ[((idx0 & 15) * WIN_CH + ((idx0 >> 4) - j0) - 3) * 16];

  i32x4 avA[4][2], avB[4][2];
  i32x4 bvA[2][2], bvB[2][2];
  i32x4 acc[8][4];
#pragma unroll
  for (int i = 0; i < 8; ++i)
#pragma unroll
    for (int j = 0; j < 4; ++j) acc[i][j] = (i32x4){0, 0, 0, 0};

#define LDA_GRP(c, msub, AV) do { \
  _Pragma("unroll") \
  for (int mi = 0; mi < 4; ++mi) { \
    const signed char* p_ = &sA[c][(wm * 128 + (msub) * 64 + mi * 16 + lr) * BKB]; \
    AV[mi][0] = *(const i32x4*)(p_ + c0); \
    AV[mi][1] = *(const i32x4*)(p_ + c1); \
  } } while (0)

#define LDB_GRP(BV, NSUB, PBP) do { \
  _Pragma("unroll") \
  for (int ni = 0; ni < 2; ++ni) \
    _Pragma("unroll") \
    for (int h = 0; h < 2; ++h) \
      BV[ni][h] = *(const i32x4*)((PBP) + (3 - 2 * (NSUB) - ni + 4 * h) * 16); \
} while (0)

#define MMA_Q(msub, nsub, AV, BV) do { \
  __builtin_amdgcn_s_setprio(1); \
  _Pragma("unroll") \
  for (int mi = 0; mi < 4; ++mi) \
    _Pragma("unroll") \
    for (int ni = 0; ni < 2; ++ni) { \
      acc[(msub) * 4 + mi][(nsub) * 2 + ni] = __builtin_amdgcn_mfma_i32_16x16x64_i8( \
          AV[mi][0], BV[ni][0], acc[(msub) * 4 + mi][(nsub) * 2 + ni], 0, 0, 0); \
      acc[(msub) * 4 + mi][(nsub) * 2 + ni] = __builtin_amdgcn_mfma_i32_16x16x64_i8( \
          AV[mi][1], BV[ni][1], acc[(msub) * 4 + mi][(nsub) * 2 + ni], 0, 0, 0); \
    } \
  __builtin_amdgcn_s_setprio(0); \
} while (0)

#define SB0() __builtin_amdgcn_sched_barrier(0)
#define BAR() __builtin_amdgcn_s_barrier()

  // Prologue: stage sPQ window + A tile 0; drain; BAR; pre-issue entry set [bvA4][avA8].
  for (int s = 0; s < 9; ++s) {
    int cc = s * 512 + t;
    if (cc < 16 * WIN_CH) {
      int rr = (int)(((unsigned long long)(unsigned)cc * 15732791ull) >> 32);  // cc/273
      int jj = cc - rr * WIN_CH;
      gld_lds16((const signed char*)(rep16 + rr * REP_CH + j0 + jj), &sPQ[cc * 16]);
    }
  }
  STG_A(0, 0, 0); STG_A(0, 0, 64); STG_A(0, 0, 128); STG_A(0, 0, 192);
  asm volatile("s_waitcnt vmcnt(0)" ::: "memory");
  BAR();
  LDB_GRP(bvA, 0, pB); SB0();
  LDA_GRP(0, 0, avA); SB0();   // DS FIFO: [bvA:4][avA:8]

  // DS FIFO ledger (steady):
  //  P0: issue bvB4 -> [bvA4 avA8 bvB4]; lgkm(4) drains entry 12; Q00(avA,bvA)
  //  P1: issue avB8 -> [bvB4 avB8];      lgkm(8) drains bvB (burst 384 < cover 650); Q01(avA,bvB)
  //  P2: lgkm(0) drains avB (768 vs cover 1300 -> ~free);        Q10(avB,bvA)
  //      then issue bvA'(4)  [after Q10's last bvA use - reg-WAR safe]
  //  P3: vmcnt(0); BAR; issue avA'8; Q11(avB,bvB) unwaited; exit [bvA'4 avA'8]
#define TILE(c, kt) do { \
  const bool st_ = (kt) + 1 < NKT; \
  LDB_GRP(bvB, 1, pB); SB0(); \
  if (st_) { STG_A((c) ^ 1, (kt) + 1, 0); STG_A((c) ^ 1, (kt) + 1, 64); \
             STG_A((c) ^ 1, (kt) + 1, 128); STG_A((c) ^ 1, (kt) + 1, 192); SB0(); } \
  asm volatile("s_waitcnt lgkmcnt(4)" ::: "memory"); SB0(); \
  MMA_Q(0, 0, avA, bvA); \
  LDA_GRP(c, 1, avB); SB0(); \
  asm volatile("s_waitcnt lgkmcnt(8)" ::: "memory"); SB0(); \
  MMA_Q(0, 1, avA, bvB); \
  asm volatile("s_waitcnt lgkmcnt(0)" ::: "memory"); SB0(); \
  MMA_Q(1, 0, avB, bvA); \
  if (st_) { LDB_GRP(bvA, 0, pB + 128); SB0(); } \
  if (st_) { asm volatile("s_waitcnt vmcnt(0)" ::: "memory"); } \
  BAR(); \
  if (st_) { LDA_GRP((c) ^ 1, 0, avA); SB0(); pB += 128; } \
  MMA_Q(1, 1, avB, bvB); \
} while (0)

  for (int kt = 0; kt < NKT; kt += 2) {
    TILE(0, kt);
    TILE(1, kt + 1);
  }

  // Epilogue: C/D col = lane&15, row = (lane>>4)*4 + reg; out = acc*sx[row]*sw + bias
  float sw = swbuf[0];
  float bvv[4];
#pragma unroll
  for (int fn = 0; fn < 4; ++fn) bvv[fn] = bias[n0 + wn * 64 + fn * 16 + lr];
#pragma unroll
  for (int fm = 0; fm < 8; ++fm) {
    int row0 = m0 + wm * 128 + fm * 16 + lk * 4;
    float sx_[4];
#pragma unroll
    for (int r = 0; r < 4; ++r) sx_[r] = sxr[row0 + r] * sw;
#pragma unroll
    for (int fn = 0; fn < 4; ++fn) {
      int col = n0 + wn * 64 + fn * 16 + lr;
#pragma unroll
      for (int r = 0; r < 4; ++r)
        C[(size_t)(row0 + r) * NDIM + col] = (float)acc[fm][fn][r] * sx_[r] + bvv[fn];
    }
  }
#undef TILE
#undef MMA_Q
#undef LDB_GRP
#undef LDA_GRP
#undef STG_A
#undef SB0
#undef BAR
}

// ---- exact-f32 fallback (used only if ws too small) ----
__global__ __launch_bounds__(256) void toep_f32_fallback(
    const float* __restrict__ X, const float* __restrict__ P,
    const float* __restrict__ bias, float* __restrict__ C)
{
  constexpr int TM = 64, TN = 64, TK = 32;
  __shared__ float xs[TM][TK + 1];
  __shared__ float win[TN + TK];
  int bm = blockIdx.x / (NDIM / TN);
  int bn = blockIdx.x % (NDIM / TN);
  int m0 = bm * TM, n0 = bn * TN;
  int t = (int)threadIdx.x;
  int tx = t & 15, ty = t >> 4;
  float acc[4][4] = {};
  for (int k0 = 0; k0 < KDIM; k0 += TK) {
    __syncthreads();
    for (int i = t; i < TM * TK; i += 256) {
      int r = i >> 5, c = i & 31;
      xs[r][c] = X[(size_t)(m0 + r) * KDIM + k0 + c];
    }
    if (t < TN + TK - 1) win[t] = P[(NDIM - 1) - n0 - (TN - 1) + k0 + t];
    __syncthreads();
    for (int kk = 0; kk < TK; ++kk) {
      float xv[4];
#pragma unroll
      for (int i = 0; i < 4; ++i) xv[i] = xs[ty * 4 + i][kk];
#pragma unroll
      for (int j = 0; j < 4; ++j) {
        float wv = win[kk + (TN - 1) - (tx * 4 + j)];
#pragma unroll
        for (int i = 0; i < 4; ++i) acc[i][j] += xv[i] * wv;
      }
    }
  }
#pragma unroll
  for (int i = 0; i < 4; ++i)
#pragma unroll
    for (int j = 0; j < 4; ++j)
      C[(size_t)(m0 + ty * 4 + i) * NDIM + n0 + tx * 4 + j] = acc[i][j] + bias[n0 + tx * 4 + j];
}

extern "C" void kernel_launch(void* const* d_in, const int* in_sizes, int n_in,
                              void* d_out, int out_size, void* d_ws, size_t ws_size,
                              hipStream_t stream) {
  const float* x = (const float*)d_in[0];
  const float* params = (const float*)d_in[1];
  const float* bias = (const float*)d_in[2];
  float* out = (float*)d_out;

  const size_t xq_off = 0;
  const size_t pq_off = (size_t)MDIM * KDIM;               // 32 MiB
  const size_t sx_off = pq_off + 16 * REP_CH * 16 + 64;
  const size_t sw_off = sx_off + (size_t)MDIM * 4;
  const size_t need = sw_off + 64;

  if (ws_size >= need) {
    signed char* xq = (signed char*)d_ws + xq_off;
    i32x4* rep16 = (i32x4*)((char*)d_ws + pq_off);
    float* sxr = (float*)((char*)d_ws + sx_off);
    float* swbuf = (float*)((char*)d_ws + sw_off);
    prep_kernel<<<1, 256, 0, stream>>>(params, swbuf, rep16);
    quant_x_kernel<<<MDIM, 256, 0, stream>>>(x, xq, sxr);
    toep_gemm_i8<<<(MDIM / BM) * (NDIM / BN), 512, 0, stream>>>(xq, rep16, bias, sxr, swbuf, out);
  } else {
    toep_f32_fallback<<<(MDIM / 64) * (NDIM / 64), 256, 0, stream>>>(x, params, bias, out);
  }
}

// Round 14
// 153.329 us; speedup vs baseline: 1.3183x; 1.0054x over previous
//
#include <hip/hip_runtime.h>

typedef __attribute__((ext_vector_type(4))) int i32x4;

#define AS1 __attribute__((address_space(1)))
#define AS3 __attribute__((address_space(3)))

constexpr int MDIM = 8192;   // batch
constexpr int NDIM = 4096;   // out features
constexpr int KDIM = 4096;   // in features

constexpr int BM = 256, BN = 256, BKB = 128;   // BKB = K-bytes (=128 i8) per tile
constexpr int NKT = KDIM / BKB;                // 32
constexpr int REP_CH = 528;                    // global table: 16-B chunks per replica
constexpr int WIN_CH = 273;                    // LDS window: 272 data chunks + 1 pad

__device__ __forceinline__ void gld_lds16(const signed char* g, signed char* l) {
  __builtin_amdgcn_global_load_lds((const AS1 void*)g, (AS3 void*)l, 16, 0, 0);
}

__device__ __forceinline__ int q8(float v, float inv) {
  return __float2int_rn(v * inv);
}

// ---- prep: w scale + 16-way byte-shift replica table (global) ----
__global__ __launch_bounds__(256) void prep_kernel(
    const float* __restrict__ params, float* __restrict__ swbuf,
    i32x4* __restrict__ rep16) {
  __shared__ signed char pql[8480];
  __shared__ float red[4];
  int t = (int)threadIdx.x;
  float m = 0.f;
  for (int i = t; i < NDIM + KDIM - 1; i += 256) m = fmaxf(m, fabsf(params[i]));
#pragma unroll
  for (int off = 32; off >= 1; off >>= 1) m = fmaxf(m, __shfl_xor(m, off));
  if ((t & 63) == 0) red[t >> 6] = m;
  __syncthreads();
  m = fmaxf(fmaxf(red[0], red[1]), fmaxf(red[2], red[3]));
  m = fmaxf(m, 1e-30f);
  float inv = 127.0f / m;
  if (t == 0) swbuf[0] = m * (1.0f / 127.0f);
  for (int i = t; i < 8480; i += 256)
    pql[i] = (i < NDIM + KDIM - 1) ? (signed char)q8(params[i], inv) : (signed char)0;
  __syncthreads();
  for (int idx = t; idx < 16 * REP_CH; idx += 256) {
    int r = idx / REP_CH, j = idx - r * REP_CH;
    const signed char* s = &pql[16 * j + r];
    i32x4 w;
#pragma unroll
    for (int d = 0; d < 4; ++d) {
      int b0 = (unsigned char)s[4 * d + 0];
      int b1 = (unsigned char)s[4 * d + 1];
      int b2 = (unsigned char)s[4 * d + 2];
      int b3 = (unsigned char)s[4 * d + 3];
      w[d] = b0 | (b1 << 8) | (b2 << 16) | (b3 << 24);
    }
    rep16[idx] = w;
  }
}

// ---- per-row x quantization: one block per row ----
__global__ __launch_bounds__(256) void quant_x_kernel(
    const float* __restrict__ x, signed char* __restrict__ xq, float* __restrict__ sxr) {
  int row = (int)blockIdx.x;
  int t = (int)threadIdx.x;
  const float4* px = (const float4*)(x + (size_t)row * KDIM) + t * 4;
  float4 v[4];
#pragma unroll
  for (int i = 0; i < 4; ++i) v[i] = px[i];
  float m = 0.f;
#pragma unroll
  for (int i = 0; i < 4; ++i)
    m = fmaxf(fmaxf(fmaxf(fabsf(v[i].x), fabsf(v[i].y)), fmaxf(fabsf(v[i].z), fabsf(v[i].w))), m);
#pragma unroll
  for (int off = 32; off >= 1; off >>= 1) m = fmaxf(m, __shfl_xor(m, off));
  __shared__ float red[4];
  if ((t & 63) == 0) red[t >> 6] = m;
  __syncthreads();
  m = fmaxf(fmaxf(red[0], red[1]), fmaxf(red[2], red[3]));
  m = fmaxf(m, 1e-30f);
  float inv = 127.0f / m;
  if (t == 0) sxr[row] = m * (1.0f / 127.0f);
  i32x4 w;
#pragma unroll
  for (int i = 0; i < 4; ++i) {
    int q0 = q8(v[i].x, inv), q1 = q8(v[i].y, inv), q2 = q8(v[i].z, inv), q3 = q8(v[i].w, inv);
    w[i] = (q0 & 0xff) | ((q1 & 0xff) << 8) | ((q2 & 0xff) << 16) | ((q3 & 0xff) << 24);
  }
  *(i32x4*)(xq + (size_t)row * KDIM + t * 16) = w;
}

// ========== 256x256 i8 GEMM, persistent-pair: 2 M-subtiles per block ==========
// R13's exact K-loop/schedule; each block (256 total = 1/CU) does bm = 2p, 2p+1
// at one n0: pq window staged once, sub0's C-stores drain under sub1's compute.
__global__ __launch_bounds__(512, 2) void toep_gemm_i8(
    const signed char* __restrict__ A,
    const i32x4* __restrict__ rep16,
    const float* __restrict__ bias,
    const float* __restrict__ sxr,
    const float* __restrict__ swbuf,
    float* __restrict__ C)
{
  __shared__ signed char sA[2][BM * BKB];          // 65536 B
  __shared__ signed char sPQ[16 * WIN_CH * 16];    // 69888 B

  constexpr int NBN = NDIM / BN;   // 16
  constexpr int NWG = (MDIM / BM / 2) * NBN;   // 256 (divisible by 8 -> bijective swizzle)
  int bid = (int)blockIdx.x;
  int swz = (bid & 7) * (NWG >> 3) + (bid >> 3);
  int bp = swz >> 4;              // M-pair index [0,16)
  int bn = swz & 15;
  int n0 = bn * BN;

  int t = (int)threadIdx.x;
  int lane = t & 63, wid = t >> 6;
  int wm = wid >> 2, wn = wid & 3;     // 2 (M) x 4 (N) waves; 128x64 per wave
  int lr = lane & 15, lk = lane >> 4;

  int scol = (((t & 7) ^ ((t >> 3) & 7)) << 4);   // bytes

  int aswz = (lr & 7) << 4;
  int c0 = (lk * 16) ^ aswz;        // k-bytes 0..63
  int c1 = (64 + lk * 16) ^ aswz;   // k-bytes 64..127

  int j0 = (3840 - n0) >> 4;
  int idx0 = 4095 - (n0 + wn * 64 + lr) + lk * 16;
  const signed char* pBbase = &sPQ[((idx0 & 15) * WIN_CH + ((idx0 >> 4) - j0) - 3) * 16];

  i32x4 avA[4][2], avB[4][2];
  i32x4 bvA[2][2], bvB[2][2];
  i32x4 acc[8][4];

#define STG_A(c, kt, R0) gld_lds16(gA + (size_t)(R0) * KDIM + (kt) * BKB, &sA[c][(R0) * BKB + t * 16])

#define LDA_GRP(c, msub, AV) do { \
  _Pragma("unroll") \
  for (int mi = 0; mi < 4; ++mi) { \
    const signed char* p_ = &sA[c][(wm * 128 + (msub) * 64 + mi * 16 + lr) * BKB]; \
    AV[mi][0] = *(const i32x4*)(p_ + c0); \
    AV[mi][1] = *(const i32x4*)(p_ + c1); \
  } } while (0)

#define LDB_GRP(BV, NSUB, PBP) do { \
  _Pragma("unroll") \
  for (int ni = 0; ni < 2; ++ni) \
    _Pragma("unroll") \
    for (int h = 0; h < 2; ++h) \
      BV[ni][h] = *(const i32x4*)((PBP) + (3 - 2 * (NSUB) - ni + 4 * h) * 16); \
} while (0)

#define MMA_Q(msub, nsub, AV, BV) do { \
  __builtin_amdgcn_s_setprio(1); \
  _Pragma("unroll") \
  for (int mi = 0; mi < 4; ++mi) \
    _Pragma("unroll") \
    for (int ni = 0; ni < 2; ++ni) { \
      acc[(msub) * 4 + mi][(nsub) * 2 + ni] = __builtin_amdgcn_mfma_i32_16x16x64_i8( \
          AV[mi][0], BV[ni][0], acc[(msub) * 4 + mi][(nsub) * 2 + ni], 0, 0, 0); \
      acc[(msub) * 4 + mi][(nsub) * 2 + ni] = __builtin_amdgcn_mfma_i32_16x16x64_i8( \
          AV[mi][1], BV[ni][1], acc[(msub) * 4 + mi][(nsub) * 2 + ni], 0, 0, 0); \
    } \
  __builtin_amdgcn_s_setprio(0); \
} while (0)

#define SB0() __builtin_amdgcn_sched_barrier(0)
#define BAR() __builtin_amdgcn_s_barrier()

  // Stage pq window ONCE per block (both subtiles share n0).
  for (int s = 0; s < 9; ++s) {
    int cc = s * 512 + t;
    if (cc < 16 * WIN_CH) {
      int rr = (int)(((unsigned long long)(unsigned)cc * 15732791ull) >> 32);  // cc/273
      int jj = cc - rr * WIN_CH;
      gld_lds16((const signed char*)(rep16 + rr * REP_CH + j0 + jj), &sPQ[cc * 16]);
    }
  }

  float sw = swbuf[0];

#define TILE(c, kt) do { \
  const bool st_ = (kt) + 1 < NKT; \
  LDB_GRP(bvB, 1, pB); SB0(); \
  if (st_) { STG_A((c) ^ 1, (kt) + 1, 0); STG_A((c) ^ 1, (kt) + 1, 64); \
             STG_A((c) ^ 1, (kt) + 1, 128); STG_A((c) ^ 1, (kt) + 1, 192); SB0(); } \
  asm volatile("s_waitcnt lgkmcnt(4)" ::: "memory"); SB0(); \
  MMA_Q(0, 0, avA, bvA); \
  LDA_GRP(c, 1, avB); SB0(); \
  asm volatile("s_waitcnt lgkmcnt(8)" ::: "memory"); SB0(); \
  MMA_Q(0, 1, avA, bvB); \
  asm volatile("s_waitcnt lgkmcnt(0)" ::: "memory"); SB0(); \
  MMA_Q(1, 0, avB, bvA); \
  if (st_) { LDB_GRP(bvA, 0, pB + 128); SB0(); } \
  if (st_) { asm volatile("s_waitcnt vmcnt(0)" ::: "memory"); } \
  BAR(); \
  if (st_) { LDA_GRP((c) ^ 1, 0, avA); SB0(); pB += 128; } \
  MMA_Q(1, 1, avB, bvB); \
} while (0)

#pragma unroll 1
  for (int sub = 0; sub < 2; ++sub) {
    int m0 = (bp * 2 + sub) * BM;
    const signed char* gA = A + (size_t)(m0 + (t >> 3)) * KDIM + scol;
    const signed char* pB = pBbase;

#pragma unroll
    for (int i = 0; i < 8; ++i)
#pragma unroll
      for (int j = 0; j < 4; ++j) acc[i][j] = (i32x4){0, 0, 0, 0};

    // Stage A tile 0 into buf0; drain (sub0: also drains window DMA;
    // sub1: also waits L2-acceptance of sub0's stores); BAR; pre-issue entry set.
    STG_A(0, 0, 0); STG_A(0, 0, 64); STG_A(0, 0, 128); STG_A(0, 0, 192);
    asm volatile("s_waitcnt vmcnt(0)" ::: "memory");
    BAR();
    LDB_GRP(bvA, 0, pB); SB0();
    LDA_GRP(0, 0, avA); SB0();   // DS FIFO: [bvA:4][avA:8]

#pragma unroll 1
    for (int kt = 0; kt < NKT; kt += 2) {
      TILE(0, kt);
      TILE(1, kt + 1);
    }

    // Epilogue: C/D col = lane&15, row = (lane>>4)*4 + reg; stores fly async.
    float bvv[4];
#pragma unroll
    for (int fn = 0; fn < 4; ++fn) bvv[fn] = bias[n0 + wn * 64 + fn * 16 + lr];
#pragma unroll
    for (int fm = 0; fm < 8; ++fm) {
      int row0 = m0 + wm * 128 + fm * 16 + lk * 4;
      float sx_[4];
#pragma unroll
      for (int r = 0; r < 4; ++r) sx_[r] = sxr[row0 + r] * sw;
#pragma unroll
      for (int fn = 0; fn < 4; ++fn) {
        int col = n0 + wn * 64 + fn * 16 + lr;
#pragma unroll
        for (int r = 0; r < 4; ++r)
          C[(size_t)(row0 + r) * NDIM + col] = (float)acc[fm][fn][r] * sx_[r] + bvv[fn];
      }
    }
    if (sub == 0) BAR();   // all waves' LDS reads done -> safe to re-stage buf0
  }
#undef TILE
#undef MMA_Q
#undef LDB_GRP
#undef LDA_GRP
#undef STG_A
#undef SB0
#undef BAR
}

// ---- exact-f32 fallback (used only if ws too small) ----
__global__ __launch_bounds__(256) void toep_f32_fallback(
    const float* __restrict__ X, const float* __restrict__ P,
    const float* __restrict__ bias, float* __restrict__ C)
{
  constexpr int TM = 64, TN = 64, TK = 32;
  __shared__ float xs[TM][TK + 1];
  __shared__ float win[TN + TK];
  int bm = blockIdx.x / (NDIM / TN);
  int bn = blockIdx.x % (NDIM / TN);
  int m0 = bm * TM, n0 = bn * TN;
  int t = (int)threadIdx.x;
  int tx = t & 15, ty = t >> 4;
  float acc[4][4] = {};
  for (int k0 = 0; k0 < KDIM; k0 += TK) {
    __syncthreads();
    for (int i = t; i < TM * TK; i += 256) {
      int r = i >> 5, c = i & 31;
      xs[r][c] = X[(size_t)(m0 + r) * KDIM + k0 + c];
    }
    if (t < TN + TK - 1) win[t] = P[(NDIM - 1) - n0 - (TN - 1) + k0 + t];
    __syncthreads();
    for (int kk = 0; kk < TK; ++kk) {
      float xv[4];
#pragma unroll
      for (int i = 0; i < 4; ++i) xv[i] = xs[ty * 4 + i][kk];
#pragma unroll
      for (int j = 0; j < 4; ++j) {
        float wv = win[kk + (TN - 1) - (tx * 4 + j)];
#pragma unroll
        for (int i = 0; i < 4; ++i) acc[i][j] += xv[i] * wv;
      }
    }
  }
#pragma unroll
  for (int i = 0; i < 4; ++i)
#pragma unroll
    for (int j = 0; j < 4; ++j)
      C[(size_t)(m0 + ty * 4 + i) * NDIM + n0 + tx * 4 + j] = acc[i][j] + bias[n0 + tx * 4 + j];
}

extern "C" void kernel_launch(void* const* d_in, const int* in_sizes, int n_in,
                              void* d_out, int out_size, void* d_ws, size_t ws_size,
                              hipStream_t stream) {
  const float* x = (const float*)d_in[0];
  const float* params = (const float*)d_in[1];
  const float* bias = (const float*)d_in[2];
  float* out = (float*)d_out;

  const size_t xq_off = 0;
  const size_t pq_off = (size_t)MDIM * KDIM;               // 32 MiB
  const size_t sx_off = pq_off + 16 * REP_CH * 16 + 64;
  const size_t sw_off = sx_off + (size_t)MDIM * 4;
  const size_t need = sw_off + 64;

  if (ws_size >= need) {
    signed char* xq = (signed char*)d_ws + xq_off;
    i32x4* rep16 = (i32x4*)((char*)d_ws + pq_off);
    float* sxr = (float*)((char*)d_ws + sx_off);
    float* swbuf = (float*)((char*)d_ws + sw_off);
    prep_kernel<<<1, 256, 0, stream>>>(params, swbuf, rep16);
    quant_x_kernel<<<MDIM, 256, 0, stream>>>(x, xq, sxr);
    toep_gemm_i8<<<(MDIM / BM / 2) * (NDIM / BN), 512, 0, stream>>>(xq, rep16, bias, sxr, swbuf, out);
  } else {
    toep_f32_fallback<<<(MDIM / 64) * (NDIM / 64), 256, 0, stream>>>(x, params, bias, out);
  }
}